// Round 16
// baseline (221.806 us; speedup 1.0000x reference)
//
#include <hip/hip_runtime.h>
#include <cstdint>
#include <cstddef>

#define NEG_SLOPE 0.2f

typedef __attribute__((ext_vector_type(8))) short short8;
typedef __attribute__((ext_vector_type(4))) float f32x4;
typedef __attribute__((ext_vector_type(4))) uint32_t u32x4;

static __device__ __forceinline__ unsigned short f2bf(float x) {
  uint32_t u = __float_as_uint(x);
  uint32_t r = (u + 0x7FFFu + ((u >> 16) & 1u)) >> 16;
  return (unsigned short)r;
}

// ---------------------------------------------------------------------------
// prep: z=0/1 -> W0/W1 transpose+cast to Wt[256][128] bf16;
//       z=2 (block x==0 only) -> Q[h][k] = sum_d Wm[k][h*32+d]*attn_r[h][d]
// ---------------------------------------------------------------------------
__global__ void prep_kernel(const float* __restrict__ W0, const float* __restrict__ W1,
                            const float* __restrict__ Wm, const float* __restrict__ ar,
                            unsigned short* __restrict__ T0, unsigned short* __restrict__ T1,
                            float* __restrict__ Q) {
  const int z = blockIdx.y;
  const int t = threadIdx.x;
  if (z < 2) {
    const float* W = (z == 0) ? W0 : W1;
    unsigned short* T = (z == 0) ? T0 : T1;
    int c = blockIdx.x * 2 + (t >> 7);
    int k = t & 127;
    T[c * 128 + k] = f2bf(W[k * 256 + c]);
  } else if (blockIdx.x == 0) {
    #pragma unroll
    for (int q4 = 0; q4 < 4; ++q4) {
      int t2 = q4 * 256 + t;
      int k = t2 >> 3, h = t2 & 7;
      const float* wr = &Wm[k * 256 + h * 32];
      const float* av = &ar[h * 32];
      float s = 0.f;
      #pragma unroll
      for (int q = 0; q < 8; ++q) {
        float4 w4 = *(const float4*)(wr + q * 4);
        float4 a4 = *(const float4*)(av + q * 4);
        s += w4.x * a4.x + w4.y * a4.y + w4.z * a4.z + w4.w * a4.w;
      }
      Q[h * 128 + k] = s;
    }
  }
}

// ---------------------------------------------------------------------------
// Fused: blocks [0, erb) -> er[n][h] = sum_k feats[n][k]*Q[h][k] (rank-8
// master projection, fp32); blocks [erb, erb+cb) -> degree count.
// ---------------------------------------------------------------------------
__global__ __launch_bounds__(256)
void er_count_kernel(const float* __restrict__ feats, const float* __restrict__ Q,
                     float* __restrict__ er, int N, int erb,
                     const int* __restrict__ dst0, int E0,
                     const int* __restrict__ dst1, int E1,
                     int* __restrict__ deg) {
  const int t = threadIdx.x;
  if (blockIdx.x >= erb) {
    int i = (blockIdx.x - erb) * 256 + t;
    int E = E0 + E1;
    if (i < E) {
      int d = (i < E0) ? dst0[i] : dst1[i - E0];
      atomicAdd(&deg[d], 1);
    }
    return;
  }

  __shared__ float Qs[8 * 128];
  ((float4*)Qs)[t] = ((const float4*)Q)[t];
  __syncthreads();

  const int lane = t & 63, wave = t >> 6;
  const int j = lane & 7;
  const int n = blockIdx.x * 32 + wave * 8 + (lane >> 3);
  const bool ok = n < N;

  float acc[8] = {};
  #pragma unroll
  for (int q = 0; q < 4; ++q) {
    float4 f = make_float4(0.f, 0.f, 0.f, 0.f);
    int kc = q * 32 + j * 4;
    if (ok) f = *(const float4*)(&feats[(size_t)n * 128 + kc]);
    #pragma unroll
    for (int h = 0; h < 8; ++h) {
      const float* qr = &Qs[h * 128 + kc];
      acc[h] = fmaf(f.x, qr[0], acc[h]);
      acc[h] = fmaf(f.y, qr[1], acc[h]);
      acc[h] = fmaf(f.z, qr[2], acc[h]);
      acc[h] = fmaf(f.w, qr[3], acc[h]);
    }
  }
  #pragma unroll
  for (int h = 0; h < 8; ++h) {
    acc[h] += __shfl_xor(acc[h], 1);
    acc[h] += __shfl_xor(acc[h], 2);
    acc[h] += __shfl_xor(acc[h], 4);
  }
  float out = acc[0];
  out = (j == 1) ? acc[1] : out;  out = (j == 2) ? acc[2] : out;
  out = (j == 3) ? acc[3] : out;  out = (j == 4) ? acc[4] : out;
  out = (j == 5) ? acc[5] : out;  out = (j == 6) ? acc[6] : out;
  out = (j == 7) ? acc[7] : out;
  if (ok) er[(size_t)n * 8 + j] = out;
}

// ---------------------------------------------------------------------------
// MFMA proj for the two attention-node types (z = 0 -> a0, z = 1 -> a1):
// ft = bf16(feats) @ bf16(W), el fused. Row tile 64 (LDS 16 KB), 4 waves
// each owning a different 64-col quarter. Wt fragments prefetched before
// staging; one barrier. Swapped-operand MFMA => D[ftcol][node]: lane l15 =
// node, regs = 4 consecutive ft cols -> direct ushort4 register stores.
// ---------------------------------------------------------------------------
__global__ __launch_bounds__(256)
void proj_mfma_kernel(const float* __restrict__ fa0, const float* __restrict__ fa1,
                      const unsigned short* __restrict__ Wt0,
                      const unsigned short* __restrict__ Wt1,
                      const float* __restrict__ attn_l,
                      int Na0, int Na1,
                      unsigned short* __restrict__ ft_all, float* __restrict__ el_all) {
  const int z = blockIdx.z;
  const float* feats = (z == 0) ? fa0 : fa1;
  const unsigned short* Wt = (z == 0) ? Wt0 : Wt1;
  const float* av = attn_l;
  const int N = (z == 0) ? Na0 : Na1;
  unsigned short* ft_out = (z == 0) ? ft_all : ft_all + (size_t)Na0 * 256;
  float* el_out = (z == 0) ? el_all : el_all + (size_t)Na0 * 8;

  const int rb = blockIdx.x * 64;
  if (rb >= N) return;

  __shared__ unsigned short As[64 * 128];   // 16 KB
  const int t = threadIdx.x;
  const int wid = t >> 6, lane = t & 63;
  const int l15 = lane & 15, l4 = lane >> 4;
  const int cbw = wid * 64;                 // this wave's col quarter
  const int head0 = cbw >> 5;               // 2 heads per wave

  // prefetch Wt fragments (L2-hot, no LDS dependency)
  short8 bf[4][4];                          // [kb][nf]
  #pragma unroll
  for (int nf = 0; nf < 4; ++nf) {
    const unsigned short* wp = &Wt[(size_t)(cbw + nf * 16 + l15) * 128];
    #pragma unroll
    for (int kb = 0; kb < 4; ++kb)
      bf[kb][nf] = *(const short8*)(wp + kb * 32 + l4 * 8);
  }

  // stage feats rows rb..rb+64: f32 -> bf16, swizzled, coalesced
  #pragma unroll
  for (int it = 0; it < 8; ++it) {
    int i = it * 256 + t;
    int r = i >> 5, kc = (i & 31) << 2;
    float4 f = make_float4(0.f, 0.f, 0.f, 0.f);
    if (rb + r < N) f = *(const float4*)(&feats[(size_t)(rb + r) * 128 + kc]);
    ushort4 u;
    u.x = f2bf(f.x); u.y = f2bf(f.y); u.z = f2bf(f.z); u.w = f2bf(f.w);
    uint32_t byte = ((uint32_t)(r * 256 + kc * 2)) ^ ((uint32_t)((r & 7) << 4));
    *(ushort4*)((char*)As + byte) = u;
  }
  __syncthreads();

  f32x4 acc[4][4];                          // [mf][nf]
  #pragma unroll
  for (int a = 0; a < 4; ++a)
    #pragma unroll
    for (int b = 0; b < 4; ++b)
      acc[a][b] = (f32x4){0.f, 0.f, 0.f, 0.f};

  #pragma unroll
  for (int kb = 0; kb < 4; ++kb) {
    short8 af[4];
    #pragma unroll
    for (int mf = 0; mf < 4; ++mf) {
      int row = mf * 16 + l15;
      uint32_t byte = ((uint32_t)(row * 256 + kb * 64 + l4 * 16)) ^ ((uint32_t)((row & 7) << 4));
      af[mf] = *(const short8*)((const char*)As + byte);
    }
    #pragma unroll
    for (int mf = 0; mf < 4; ++mf)
      #pragma unroll
      for (int nf = 0; nf < 4; ++nf)
        acc[mf][nf] = __builtin_amdgcn_mfma_f32_16x16x32_bf16(
            bf[kb][nf], af[mf], acc[mf][nf], 0, 0, 0);
  }

  float avf[4][4];
  #pragma unroll
  for (int nf = 0; nf < 4; ++nf)
    #pragma unroll
    for (int reg = 0; reg < 4; ++reg)
      avf[nf][reg] = av[(head0 + (nf >> 1)) * 32 + (nf & 1) * 16 + l4 * 4 + reg];

  #pragma unroll
  for (int mf = 0; mf < 4; ++mf) {
    int node = rb + mf * 16 + l15;
    bool ok = node < N;
    if (ok) {
      size_t base = (size_t)node * 256 + cbw + l4 * 4;
      #pragma unroll
      for (int nf = 0; nf < 4; ++nf) {
        ushort4 u;
        u.x = f2bf(acc[mf][nf][0]); u.y = f2bf(acc[mf][nf][1]);
        u.z = f2bf(acc[mf][nf][2]); u.w = f2bf(acc[mf][nf][3]);
        *(ushort4*)(&ft_out[base + nf * 16]) = u;
      }
    }
    #pragma unroll
    for (int hh = 0; hh < 2; ++hh) {
      float p = 0.f;
      #pragma unroll
      for (int reg = 0; reg < 4; ++reg) {
        p = fmaf(acc[mf][2 * hh][reg], avf[2 * hh][reg], p);
        p = fmaf(acc[mf][2 * hh + 1][reg], avf[2 * hh + 1][reg], p);
      }
      p += __shfl_xor(p, 16);
      p += __shfl_xor(p, 32);
      if (ok && l4 == 0)
        el_out[(size_t)node * 8 + head0 + hh] = p;
    }
  }
}

// ---------------------------------------------------------------------------
__global__ __launch_bounds__(1024)
void block_reduce_kernel(const int* __restrict__ deg, int* __restrict__ partial, int n) {
  __shared__ int wsum[16];
  const int t = threadIdx.x;
  int idx = blockIdx.x * 1024 + t;
  int v = (idx < n) ? deg[idx] : 0;
  #pragma unroll
  for (int off = 1; off < 64; off <<= 1) v += __shfl_xor(v, off);
  if ((t & 63) == 0) wsum[t >> 6] = v;
  __syncthreads();
  if (t < 16) {
    int x = wsum[t];
    #pragma unroll
    for (int off = 1; off < 16; off <<= 1) x += __shfl_xor(x, off);
    if (t == 0) partial[blockIdx.x] = x;
  }
}

__global__ __launch_bounds__(64)
void partial_scan_kernel(const int* __restrict__ partial, int* __restrict__ base,
                         int nb, int* __restrict__ offs, int n) {
  const int t = threadIdx.x;
  int v = (t < nb) ? partial[t] : 0;
  int incl = v;
  #pragma unroll
  for (int off = 1; off < 64; off <<= 1) {
    int x = __shfl_up(incl, off);
    if (t >= off) incl += x;
  }
  if (t < nb) base[t] = incl - v;
  if (t == nb - 1) offs[n] = incl;
}

__global__ __launch_bounds__(1024)
void apply_scan_kernel(const int* __restrict__ deg, const int* __restrict__ base,
                       int* __restrict__ offs, int* __restrict__ cursor, int n) {
  __shared__ int wsum[16];
  const int t = threadIdx.x;
  const int idx = blockIdx.x * 1024 + t;
  int v = (idx < n) ? deg[idx] : 0;
  const int lane = t & 63, w = t >> 6;
  int incl = v;
  #pragma unroll
  for (int off = 1; off < 64; off <<= 1) {
    int x = __shfl_up(incl, off);
    if (lane >= off) incl += x;
  }
  if (lane == 63) wsum[w] = incl;
  __syncthreads();
  if (t < 16) {
    int x = wsum[t];
    #pragma unroll
    for (int off = 1; off < 16; off <<= 1) {
      int y = __shfl_up(x, off);
      if (t >= off) x += y;
    }
    wsum[t] = x;
  }
  __syncthreads();
  int excl = base[blockIdx.x] + ((w > 0) ? wsum[w - 1] : 0) + incl - v;
  if (idx < n) {
    offs[idx] = excl;
    cursor[idx] = excl;
  }
}

// ---------------------------------------------------------------------------
// scatter: per edge, one 32-byte-aligned record {src, w[8] bf16} at the CSR
// slot, written NONTEMPORAL: records are read sequentially (scalar loads) by
// aggregate, never gathered -- nt keeps this kernel's L2 free for the el/er
// gather tables (4.8 MB) instead of thrashing it with 51 MB of write lines.
// Weights are exp(lrelu(el[src]+er[dst])): single-pass softmax, O(1)-bounded.
// ---------------------------------------------------------------------------
__global__ void scatter_kernel(const int* __restrict__ src0, const int* __restrict__ dst0, int E0,
                               const int* __restrict__ src1, const int* __restrict__ dst1, int E1,
                               int* __restrict__ cursor, char* __restrict__ recs,
                               const float* __restrict__ el, const float* __restrict__ er,
                               int Na0) {
  int E = E0 + E1;
  int i = blockIdx.x * blockDim.x + threadIdx.x;
  if (i >= E) return;
  int s, d;
  if (i < E0) { s = src0[i]; d = dst0[i]; }
  else        { s = src1[i - E0] + Na0; d = dst1[i - E0]; }
  int pos = atomicAdd(&cursor[d], 1);

  const float* elp = &el[(size_t)s * 8];
  const float* erp = &er[(size_t)d * 8];
  float4 ea = *(const float4*)elp, eb = *(const float4*)(elp + 4);
  float4 ra = *(const float4*)erp, rb = *(const float4*)(erp + 4);
  float w[8];
  w[0] = ea.x + ra.x; w[1] = ea.y + ra.y; w[2] = ea.z + ra.z; w[3] = ea.w + ra.w;
  w[4] = eb.x + rb.x; w[5] = eb.y + rb.y; w[6] = eb.z + rb.z; w[7] = eb.w + rb.w;
  uint32_t pk[4];
  #pragma unroll
  for (int q = 0; q < 4; ++q) {
    float v0 = w[2 * q], v1 = w[2 * q + 1];
    v0 = fmaxf(v0, NEG_SLOPE * v0);
    v1 = fmaxf(v1, NEG_SLOPE * v1);
    uint32_t b0 = f2bf(__expf(v0)), b1 = f2bf(__expf(v1));
    pk[q] = b0 | (b1 << 16);
  }
  char* rp = recs + ((size_t)(uint32_t)pos << 5);
  u32x4 head = {(uint32_t)s, pk[0], pk[1], pk[2]};
  __builtin_nontemporal_store(head, (u32x4*)rp);
  __builtin_nontemporal_store(pk[3], (uint32_t*)(rp + 16));
}

// ---------------------------------------------------------------------------
// one wave per dst node. Records are wave-uniform -> readfirstlane pins the
// record/offs loads to the SCALAR path; src lands in an SGPR so the ft gather
// is saddr + loop-invariant lane offset. Weight picked from 4 SGPRs by 3
// cndmask + shift.
// lane layout: h = lane>>3, d = (lane&7)*4 + j
// ---------------------------------------------------------------------------
__global__ __launch_bounds__(256)
void aggregate_kernel(const int* __restrict__ offs, const char* __restrict__ recs,
                      const unsigned short* __restrict__ ft,
                      float* __restrict__ rst, int Nm) {
  int gid = blockIdx.x * blockDim.x + threadIdx.x;
  int n = gid >> 6;
  int lane = threadIdx.x & 63;
  if (n >= Nm) return;
  const int nu = __builtin_amdgcn_readfirstlane(n);   // wave-uniform node id
  const int beg = offs[nu], end = offs[nu + 1];       // scalar loads
  const int h = lane >> 3;
  const char* ftl = (const char*)ft + lane * 8;
  float o0 = 0.f, o1 = 0.f, o2 = 0.f, o3 = 0.f;
  float sw = 0.f;

  #pragma unroll 8
  for (int i = beg; i < end; ++i) {
    const uint32_t* rp = (const uint32_t*)(recs + ((size_t)(uint32_t)i << 5));
    uint32_t sct = rp[0];                         // SGPR: src index
    uint32_t d0 = rp[1], d1 = rp[2], d2 = rp[3], d3 = rp[4];   // SGPR: weights
    uint2 g = *(const uint2*)(ftl + ((size_t)sct << 9));        // the only gather
    uint32_t wa = (h & 2) ? d1 : d0;
    uint32_t wb = (h & 2) ? d3 : d2;
    uint32_t wsl = (h & 4) ? wb : wa;
    float w = __uint_as_float((h & 1) ? (wsl & 0xffff0000u) : (wsl << 16));
    sw += w;
    o0 = fmaf(w, __uint_as_float(g.x << 16), o0);
    o1 = fmaf(w, __uint_as_float(g.x & 0xffff0000u), o1);
    o2 = fmaf(w, __uint_as_float(g.y << 16), o2);
    o3 = fmaf(w, __uint_as_float(g.y & 0xffff0000u), o3);
  }

  if (beg < end) {
    float inv = 1.0f / sw;
    o0 *= inv; o1 *= inv; o2 *= inv; o3 *= inv;
  }
  *(float4*)(&rst[(size_t)n * 256 + lane * 4]) = make_float4(o0, o1, o2, o3);
}

// ---------------------------------------------------------------------------
extern "C" void kernel_launch(void* const* d_in, const int* in_sizes, int n_in,
                              void* d_out, int out_size, void* d_ws, size_t ws_size,
                              hipStream_t stream) {
  const float* master = (const float*)d_in[0];
  const float* af0    = (const float*)d_in[1];
  const float* af1    = (const float*)d_in[2];
  const int*   src0   = (const int*)d_in[3];
  const int*   dst0   = (const int*)d_in[4];
  const int*   src1   = (const int*)d_in[5];
  const int*   dst1   = (const int*)d_in[6];
  const float* Wm     = (const float*)d_in[7];
  const float* W0     = (const float*)d_in[8];
  const float* W1     = (const float*)d_in[9];
  const float* attn_l = (const float*)d_in[10];
  const float* attn_r = (const float*)d_in[11];

  const int Nm  = in_sizes[0] / 128;
  const int Na0 = in_sizes[1] / 128;
  const int Na1 = in_sizes[2] / 128;
  const int E0  = in_sizes[3];
  const int E1  = in_sizes[5];
  float* rst = (float*)d_out;

  char* ws = (char*)d_ws;
  size_t off = 0;
  auto alloc = [&](size_t b) -> char* {
    char* p = ws + off;
    off += (b + 511) & ~(size_t)511;
    return p;
  };
  unsigned short* ft = (unsigned short*)alloc((size_t)(Na0 + Na1) * 256 * sizeof(unsigned short));
  float* el = (float*)alloc((size_t)(Na0 + Na1) * 8 * sizeof(float));
  float* er = (float*)alloc((size_t)Nm * 8 * sizeof(float));
  unsigned short* Wt0 = (unsigned short*)alloc(256 * 128 * sizeof(unsigned short));
  unsigned short* Wt1 = (unsigned short*)alloc(256 * 128 * sizeof(unsigned short));
  float* Q     = (float*)alloc(8 * 128 * sizeof(float));
  int* deg     = (int*)alloc((size_t)Nm * sizeof(int));
  int* offs    = (int*)alloc((size_t)(Nm + 1) * sizeof(int));
  int* cursor  = (int*)alloc((size_t)Nm * sizeof(int));
  int* partial = (int*)alloc(64 * sizeof(int));
  int* pbase   = (int*)alloc(64 * sizeof(int));
  char* recs   = alloc((size_t)(E0 + E1) * 32);

  const int E = E0 + E1;
  hipMemsetAsync(deg, 0, (size_t)Nm * sizeof(int), stream);

  // prep: Wt0/Wt1 transpose+cast (z=0/1) + master rank-8 collapse Q (z=2)
  prep_kernel<<<dim3(128, 3), 256, 0, stream>>>(W0, W1, Wm, attn_r, Wt0, Wt1, Q);

  // er skinny GEMM + degree count, one fused launch
  const int erb = (Nm + 31) / 32;
  const int cb  = (E + 255) / 256;
  er_count_kernel<<<erb + cb, 256, 0, stream>>>(master, Q, er, Nm, erb,
                                                dst0, E0, dst1, E1, deg);

  // attention-node projections (ft + el)
  int Nmax = Na0 > Na1 ? Na0 : Na1;
  const int mb = (Nmax + 63) / 64;
  proj_mfma_kernel<<<dim3(mb, 1, 2), 256, 0, stream>>>(
      af0, af1, Wt0, Wt1, attn_l, Na0, Na1, ft, el);

  // CSR scan
  const int nb = (Nm + 1023) / 1024;   // <= 64
  block_reduce_kernel<<<nb, 1024, 0, stream>>>(deg, partial, Nm);
  partial_scan_kernel<<<1, 64, 0, stream>>>(partial, pbase, nb, offs, Nm);
  apply_scan_kernel<<<nb, 1024, 0, stream>>>(deg, pbase, offs, cursor, Nm);

  scatter_kernel<<<cb, 256, 0, stream>>>(src0, dst0, E0, src1, dst1, E1,
                                         cursor, recs, el, er, Na0);

  aggregate_kernel<<<(Nm + 3) / 4, 256, 0, stream>>>(offs, recs, ft, rst, Nm);
}

// Round 17
// 211.405 us; speedup vs baseline: 1.0492x; 1.0492x over previous
//
#include <hip/hip_runtime.h>
#include <cstdint>
#include <cstddef>

#define NEG_SLOPE 0.2f

typedef __attribute__((ext_vector_type(8))) short short8;
typedef __attribute__((ext_vector_type(4))) float f32x4;

static __device__ __forceinline__ unsigned short f2bf(float x) {
  uint32_t u = __float_as_uint(x);
  uint32_t r = (u + 0x7FFFu + ((u >> 16) & 1u)) >> 16;
  return (unsigned short)r;
}

// ---------------------------------------------------------------------------
// prep: z=0/1 -> W0/W1 transpose+cast to Wt[256][128] bf16;
//       z=2 (block x==0 only) -> Q[h][k] = sum_d Wm[k][h*32+d]*attn_r[h][d]
// ---------------------------------------------------------------------------
__global__ void prep_kernel(const float* __restrict__ W0, const float* __restrict__ W1,
                            const float* __restrict__ Wm, const float* __restrict__ ar,
                            unsigned short* __restrict__ T0, unsigned short* __restrict__ T1,
                            float* __restrict__ Q) {
  const int z = blockIdx.y;
  const int t = threadIdx.x;
  if (z < 2) {
    const float* W = (z == 0) ? W0 : W1;
    unsigned short* T = (z == 0) ? T0 : T1;
    int c = blockIdx.x * 2 + (t >> 7);
    int k = t & 127;
    T[c * 128 + k] = f2bf(W[k * 256 + c]);
  } else if (blockIdx.x == 0) {
    #pragma unroll
    for (int q4 = 0; q4 < 4; ++q4) {
      int t2 = q4 * 256 + t;
      int k = t2 >> 3, h = t2 & 7;
      const float* wr = &Wm[k * 256 + h * 32];
      const float* av = &ar[h * 32];
      float s = 0.f;
      #pragma unroll
      for (int q = 0; q < 8; ++q) {
        float4 w4 = *(const float4*)(wr + q * 4);
        float4 a4 = *(const float4*)(av + q * 4);
        s += w4.x * a4.x + w4.y * a4.y + w4.z * a4.z + w4.w * a4.w;
      }
      Q[h * 128 + k] = s;
    }
  }
}

// ---------------------------------------------------------------------------
// Fused: blocks [0, erb) -> er[n][h] = sum_k feats[n][k]*Q[h][k] (rank-8
// master projection, fp32); blocks [erb, erb+cb) -> degree count.
// ---------------------------------------------------------------------------
__global__ __launch_bounds__(256)
void er_count_kernel(const float* __restrict__ feats, const float* __restrict__ Q,
                     float* __restrict__ er, int N, int erb,
                     const int* __restrict__ dst0, int E0,
                     const int* __restrict__ dst1, int E1,
                     int* __restrict__ deg) {
  const int t = threadIdx.x;
  if (blockIdx.x >= erb) {
    int i = (blockIdx.x - erb) * 256 + t;
    int E = E0 + E1;
    if (i < E) {
      int d = (i < E0) ? dst0[i] : dst1[i - E0];
      atomicAdd(&deg[d], 1);
    }
    return;
  }

  __shared__ float Qs[8 * 128];
  ((float4*)Qs)[t] = ((const float4*)Q)[t];
  __syncthreads();

  const int lane = t & 63, wave = t >> 6;
  const int j = lane & 7;
  const int n = blockIdx.x * 32 + wave * 8 + (lane >> 3);
  const bool ok = n < N;

  float acc[8] = {};
  #pragma unroll
  for (int q = 0; q < 4; ++q) {
    float4 f = make_float4(0.f, 0.f, 0.f, 0.f);
    int kc = q * 32 + j * 4;
    if (ok) f = *(const float4*)(&feats[(size_t)n * 128 + kc]);
    #pragma unroll
    for (int h = 0; h < 8; ++h) {
      const float* qr = &Qs[h * 128 + kc];
      acc[h] = fmaf(f.x, qr[0], acc[h]);
      acc[h] = fmaf(f.y, qr[1], acc[h]);
      acc[h] = fmaf(f.z, qr[2], acc[h]);
      acc[h] = fmaf(f.w, qr[3], acc[h]);
    }
  }
  #pragma unroll
  for (int h = 0; h < 8; ++h) {
    acc[h] += __shfl_xor(acc[h], 1);
    acc[h] += __shfl_xor(acc[h], 2);
    acc[h] += __shfl_xor(acc[h], 4);
  }
  float out = acc[0];
  out = (j == 1) ? acc[1] : out;  out = (j == 2) ? acc[2] : out;
  out = (j == 3) ? acc[3] : out;  out = (j == 4) ? acc[4] : out;
  out = (j == 5) ? acc[5] : out;  out = (j == 6) ? acc[6] : out;
  out = (j == 7) ? acc[7] : out;
  if (ok) er[(size_t)n * 8 + j] = out;
}

// ---------------------------------------------------------------------------
// MFMA proj for the two attention-node types (z = 0 -> a0, z = 1 -> a1):
// ft = bf16(feats) @ bf16(W), el fused. Row tile 64 (LDS 16 KB), 4 waves
// each owning a different 64-col quarter. Wt fragments prefetched before
// staging; one barrier. Swapped-operand MFMA => D[ftcol][node]: lane l15 =
// node, regs = 4 consecutive ft cols -> direct ushort4 register stores.
// ---------------------------------------------------------------------------
__global__ __launch_bounds__(256)
void proj_mfma_kernel(const float* __restrict__ fa0, const float* __restrict__ fa1,
                      const unsigned short* __restrict__ Wt0,
                      const unsigned short* __restrict__ Wt1,
                      const float* __restrict__ attn_l,
                      int Na0, int Na1,
                      unsigned short* __restrict__ ft_all, float* __restrict__ el_all) {
  const int z = blockIdx.z;
  const float* feats = (z == 0) ? fa0 : fa1;
  const unsigned short* Wt = (z == 0) ? Wt0 : Wt1;
  const float* av = attn_l;
  const int N = (z == 0) ? Na0 : Na1;
  unsigned short* ft_out = (z == 0) ? ft_all : ft_all + (size_t)Na0 * 256;
  float* el_out = (z == 0) ? el_all : el_all + (size_t)Na0 * 8;

  const int rb = blockIdx.x * 64;
  if (rb >= N) return;

  __shared__ unsigned short As[64 * 128];   // 16 KB
  const int t = threadIdx.x;
  const int wid = t >> 6, lane = t & 63;
  const int l15 = lane & 15, l4 = lane >> 4;
  const int cbw = wid * 64;                 // this wave's col quarter
  const int head0 = cbw >> 5;               // 2 heads per wave

  // prefetch Wt fragments (L2-hot, no LDS dependency)
  short8 bf[4][4];                          // [kb][nf]
  #pragma unroll
  for (int nf = 0; nf < 4; ++nf) {
    const unsigned short* wp = &Wt[(size_t)(cbw + nf * 16 + l15) * 128];
    #pragma unroll
    for (int kb = 0; kb < 4; ++kb)
      bf[kb][nf] = *(const short8*)(wp + kb * 32 + l4 * 8);
  }

  // stage feats rows rb..rb+64: f32 -> bf16, swizzled, coalesced
  #pragma unroll
  for (int it = 0; it < 8; ++it) {
    int i = it * 256 + t;
    int r = i >> 5, kc = (i & 31) << 2;
    float4 f = make_float4(0.f, 0.f, 0.f, 0.f);
    if (rb + r < N) f = *(const float4*)(&feats[(size_t)(rb + r) * 128 + kc]);
    ushort4 u;
    u.x = f2bf(f.x); u.y = f2bf(f.y); u.z = f2bf(f.z); u.w = f2bf(f.w);
    uint32_t byte = ((uint32_t)(r * 256 + kc * 2)) ^ ((uint32_t)((r & 7) << 4));
    *(ushort4*)((char*)As + byte) = u;
  }
  __syncthreads();

  f32x4 acc[4][4];                          // [mf][nf]
  #pragma unroll
  for (int a = 0; a < 4; ++a)
    #pragma unroll
    for (int b = 0; b < 4; ++b)
      acc[a][b] = (f32x4){0.f, 0.f, 0.f, 0.f};

  #pragma unroll
  for (int kb = 0; kb < 4; ++kb) {
    short8 af[4];
    #pragma unroll
    for (int mf = 0; mf < 4; ++mf) {
      int row = mf * 16 + l15;
      uint32_t byte = ((uint32_t)(row * 256 + kb * 64 + l4 * 16)) ^ ((uint32_t)((row & 7) << 4));
      af[mf] = *(const short8*)((const char*)As + byte);
    }
    #pragma unroll
    for (int mf = 0; mf < 4; ++mf)
      #pragma unroll
      for (int nf = 0; nf < 4; ++nf)
        acc[mf][nf] = __builtin_amdgcn_mfma_f32_16x16x32_bf16(
            bf[kb][nf], af[mf], acc[mf][nf], 0, 0, 0);
  }

  float avf[4][4];
  #pragma unroll
  for (int nf = 0; nf < 4; ++nf)
    #pragma unroll
    for (int reg = 0; reg < 4; ++reg)
      avf[nf][reg] = av[(head0 + (nf >> 1)) * 32 + (nf & 1) * 16 + l4 * 4 + reg];

  #pragma unroll
  for (int mf = 0; mf < 4; ++mf) {
    int node = rb + mf * 16 + l15;
    bool ok = node < N;
    if (ok) {
      size_t base = (size_t)node * 256 + cbw + l4 * 4;
      #pragma unroll
      for (int nf = 0; nf < 4; ++nf) {
        ushort4 u;
        u.x = f2bf(acc[mf][nf][0]); u.y = f2bf(acc[mf][nf][1]);
        u.z = f2bf(acc[mf][nf][2]); u.w = f2bf(acc[mf][nf][3]);
        *(ushort4*)(&ft_out[base + nf * 16]) = u;
      }
    }
    #pragma unroll
    for (int hh = 0; hh < 2; ++hh) {
      float p = 0.f;
      #pragma unroll
      for (int reg = 0; reg < 4; ++reg) {
        p = fmaf(acc[mf][2 * hh][reg], avf[2 * hh][reg], p);
        p = fmaf(acc[mf][2 * hh + 1][reg], avf[2 * hh + 1][reg], p);
      }
      p += __shfl_xor(p, 16);
      p += __shfl_xor(p, 32);
      if (ok && l4 == 0)
        el_out[(size_t)node * 8 + head0 + hh] = p;
    }
  }
}

// ---------------------------------------------------------------------------
__global__ __launch_bounds__(1024)
void block_reduce_kernel(const int* __restrict__ deg, int* __restrict__ partial, int n) {
  __shared__ int wsum[16];
  const int t = threadIdx.x;
  int idx = blockIdx.x * 1024 + t;
  int v = (idx < n) ? deg[idx] : 0;
  #pragma unroll
  for (int off = 1; off < 64; off <<= 1) v += __shfl_xor(v, off);
  if ((t & 63) == 0) wsum[t >> 6] = v;
  __syncthreads();
  if (t < 16) {
    int x = wsum[t];
    #pragma unroll
    for (int off = 1; off < 16; off <<= 1) x += __shfl_xor(x, off);
    if (t == 0) partial[blockIdx.x] = x;
  }
}

__global__ __launch_bounds__(64)
void partial_scan_kernel(const int* __restrict__ partial, int* __restrict__ base,
                         int nb, int* __restrict__ offs, int n) {
  const int t = threadIdx.x;
  int v = (t < nb) ? partial[t] : 0;
  int incl = v;
  #pragma unroll
  for (int off = 1; off < 64; off <<= 1) {
    int x = __shfl_up(incl, off);
    if (t >= off) incl += x;
  }
  if (t < nb) base[t] = incl - v;
  if (t == nb - 1) offs[n] = incl;
}

__global__ __launch_bounds__(1024)
void apply_scan_kernel(const int* __restrict__ deg, const int* __restrict__ base,
                       int* __restrict__ offs, int* __restrict__ cursor, int n) {
  __shared__ int wsum[16];
  const int t = threadIdx.x;
  const int idx = blockIdx.x * 1024 + t;
  int v = (idx < n) ? deg[idx] : 0;
  const int lane = t & 63, w = t >> 6;
  int incl = v;
  #pragma unroll
  for (int off = 1; off < 64; off <<= 1) {
    int x = __shfl_up(incl, off);
    if (lane >= off) incl += x;
  }
  if (lane == 63) wsum[w] = incl;
  __syncthreads();
  if (t < 16) {
    int x = wsum[t];
    #pragma unroll
    for (int off = 1; off < 16; off <<= 1) {
      int y = __shfl_up(x, off);
      if (t >= off) x += y;
    }
    wsum[t] = x;
  }
  __syncthreads();
  int excl = base[blockIdx.x] + ((w > 0) ? wsum[w - 1] : 0) + incl - v;
  if (idx < n) {
    offs[idx] = excl;
    cursor[idx] = excl;
  }
}

// ---------------------------------------------------------------------------
// scatter: per edge, one 32-byte-aligned record {src, w[8] bf16} (20 B used)
// at the CSR slot, written with PLAIN stores (L2-resident for aggregate's
// sequential scalar reads -- nt here cost +12 us in R16).
// Weights are exp(lrelu(el[src]+er[dst])): single-pass softmax, O(1)-bounded.
// ---------------------------------------------------------------------------
__global__ void scatter_kernel(const int* __restrict__ src0, const int* __restrict__ dst0, int E0,
                               const int* __restrict__ src1, const int* __restrict__ dst1, int E1,
                               int* __restrict__ cursor, char* __restrict__ recs,
                               const float* __restrict__ el, const float* __restrict__ er,
                               int Na0) {
  int E = E0 + E1;
  int i = blockIdx.x * blockDim.x + threadIdx.x;
  if (i >= E) return;
  int s, d;
  if (i < E0) { s = src0[i]; d = dst0[i]; }
  else        { s = src1[i - E0] + Na0; d = dst1[i - E0]; }
  int pos = atomicAdd(&cursor[d], 1);

  const float* elp = &el[(size_t)s * 8];
  const float* erp = &er[(size_t)d * 8];
  float4 ea = *(const float4*)elp, eb = *(const float4*)(elp + 4);
  float4 ra = *(const float4*)erp, rb = *(const float4*)(erp + 4);
  float w[8];
  w[0] = ea.x + ra.x; w[1] = ea.y + ra.y; w[2] = ea.z + ra.z; w[3] = ea.w + ra.w;
  w[4] = eb.x + rb.x; w[5] = eb.y + rb.y; w[6] = eb.z + rb.z; w[7] = eb.w + rb.w;
  uint32_t pk[4];
  #pragma unroll
  for (int q = 0; q < 4; ++q) {
    float v0 = w[2 * q], v1 = w[2 * q + 1];
    v0 = fmaxf(v0, NEG_SLOPE * v0);
    v1 = fmaxf(v1, NEG_SLOPE * v1);
    uint32_t b0 = f2bf(__expf(v0)), b1 = f2bf(__expf(v1));
    pk[q] = b0 | (b1 << 16);
  }
  char* rp = recs + ((size_t)(uint32_t)pos << 5);
  *(uint4*)rp = make_uint4((uint32_t)s, pk[0], pk[1], pk[2]);
  *(uint32_t*)(rp + 16) = pk[3];
}

// ---------------------------------------------------------------------------
// one wave per dst node. Records are wave-uniform -> readfirstlane pins the
// record/offs loads to the SCALAR path; src lands in an SGPR so the ft gather
// is saddr + loop-invariant lane offset. Weight picked from 4 SGPRs by 3
// cndmask + shift.
// lane layout: h = lane>>3, d = (lane&7)*4 + j
// ---------------------------------------------------------------------------
__global__ __launch_bounds__(256)
void aggregate_kernel(const int* __restrict__ offs, const char* __restrict__ recs,
                      const unsigned short* __restrict__ ft,
                      float* __restrict__ rst, int Nm) {
  int gid = blockIdx.x * blockDim.x + threadIdx.x;
  int n = gid >> 6;
  int lane = threadIdx.x & 63;
  if (n >= Nm) return;
  const int nu = __builtin_amdgcn_readfirstlane(n);   // wave-uniform node id
  const int beg = offs[nu], end = offs[nu + 1];       // scalar loads
  const int h = lane >> 3;
  const char* ftl = (const char*)ft + lane * 8;
  float o0 = 0.f, o1 = 0.f, o2 = 0.f, o3 = 0.f;
  float sw = 0.f;

  #pragma unroll 8
  for (int i = beg; i < end; ++i) {
    const uint32_t* rp = (const uint32_t*)(recs + ((size_t)(uint32_t)i << 5));
    uint32_t sct = rp[0];                         // SGPR: src index
    uint32_t d0 = rp[1], d1 = rp[2], d2 = rp[3], d3 = rp[4];   // SGPR: weights
    uint2 g = *(const uint2*)(ftl + ((size_t)sct << 9));        // the only gather
    uint32_t wa = (h & 2) ? d1 : d0;
    uint32_t wb = (h & 2) ? d3 : d2;
    uint32_t wsl = (h & 4) ? wb : wa;
    float w = __uint_as_float((h & 1) ? (wsl & 0xffff0000u) : (wsl << 16));
    sw += w;
    o0 = fmaf(w, __uint_as_float(g.x << 16), o0);
    o1 = fmaf(w, __uint_as_float(g.x & 0xffff0000u), o1);
    o2 = fmaf(w, __uint_as_float(g.y << 16), o2);
    o3 = fmaf(w, __uint_as_float(g.y & 0xffff0000u), o3);
  }

  if (beg < end) {
    float inv = 1.0f / sw;
    o0 *= inv; o1 *= inv; o2 *= inv; o3 *= inv;
  }
  *(float4*)(&rst[(size_t)n * 256 + lane * 4]) = make_float4(o0, o1, o2, o3);
}

// ---------------------------------------------------------------------------
extern "C" void kernel_launch(void* const* d_in, const int* in_sizes, int n_in,
                              void* d_out, int out_size, void* d_ws, size_t ws_size,
                              hipStream_t stream) {
  const float* master = (const float*)d_in[0];
  const float* af0    = (const float*)d_in[1];
  const float* af1    = (const float*)d_in[2];
  const int*   src0   = (const int*)d_in[3];
  const int*   dst0   = (const int*)d_in[4];
  const int*   src1   = (const int*)d_in[5];
  const int*   dst1   = (const int*)d_in[6];
  const float* Wm     = (const float*)d_in[7];
  const float* W0     = (const float*)d_in[8];
  const float* W1     = (const float*)d_in[9];
  const float* attn_l = (const float*)d_in[10];
  const float* attn_r = (const float*)d_in[11];

  const int Nm  = in_sizes[0] / 128;
  const int Na0 = in_sizes[1] / 128;
  const int Na1 = in_sizes[2] / 128;
  const int E0  = in_sizes[3];
  const int E1  = in_sizes[5];
  float* rst = (float*)d_out;

  char* ws = (char*)d_ws;
  size_t off = 0;
  auto alloc = [&](size_t b) -> char* {
    char* p = ws + off;
    off += (b + 511) & ~(size_t)511;
    return p;
  };
  unsigned short* ft = (unsigned short*)alloc((size_t)(Na0 + Na1) * 256 * sizeof(unsigned short));
  float* el = (float*)alloc((size_t)(Na0 + Na1) * 8 * sizeof(float));
  float* er = (float*)alloc((size_t)Nm * 8 * sizeof(float));
  unsigned short* Wt0 = (unsigned short*)alloc(256 * 128 * sizeof(unsigned short));
  unsigned short* Wt1 = (unsigned short*)alloc(256 * 128 * sizeof(unsigned short));
  float* Q     = (float*)alloc(8 * 128 * sizeof(float));
  int* deg     = (int*)alloc((size_t)Nm * sizeof(int));
  int* offs    = (int*)alloc((size_t)(Nm + 1) * sizeof(int));
  int* cursor  = (int*)alloc((size_t)Nm * sizeof(int));
  int* partial = (int*)alloc(64 * sizeof(int));
  int* pbase   = (int*)alloc(64 * sizeof(int));
  char* recs   = alloc((size_t)(E0 + E1) * 32);

  const int E = E0 + E1;
  hipMemsetAsync(deg, 0, (size_t)Nm * sizeof(int), stream);

  // prep: Wt0/Wt1 transpose+cast (z=0/1) + master rank-8 collapse Q (z=2)
  prep_kernel<<<dim3(128, 3), 256, 0, stream>>>(W0, W1, Wm, attn_r, Wt0, Wt1, Q);

  // er skinny GEMM + degree count, one fused launch
  const int erb = (Nm + 31) / 32;
  const int cb  = (E + 255) / 256;
  er_count_kernel<<<erb + cb, 256, 0, stream>>>(master, Q, er, Nm, erb,
                                                dst0, E0, dst1, E1, deg);

  // attention-node projections (ft + el)
  int Nmax = Na0 > Na1 ? Na0 : Na1;
  const int mb = (Nmax + 63) / 64;
  proj_mfma_kernel<<<dim3(mb, 1, 2), 256, 0, stream>>>(
      af0, af1, Wt0, Wt1, attn_l, Na0, Na1, ft, el);

  // CSR scan
  const int nb = (Nm + 1023) / 1024;   // <= 64
  block_reduce_kernel<<<nb, 1024, 0, stream>>>(deg, partial, Nm);
  partial_scan_kernel<<<1, 64, 0, stream>>>(partial, pbase, nb, offs, Nm);
  apply_scan_kernel<<<nb, 1024, 0, stream>>>(deg, pbase, offs, cursor, Nm);

  scatter_kernel<<<cb, 256, 0, stream>>>(src0, dst0, E0, src1, dst1, E1,
                                         cursor, recs, el, er, Na0);

  aggregate_kernel<<<(Nm + 3) / 4, 256, 0, stream>>>(offs, recs, ft, rst, Nm);
}

// Round 18
// 210.612 us; speedup vs baseline: 1.0532x; 1.0038x over previous
//
#include <hip/hip_runtime.h>
#include <cstdint>
#include <cstddef>

#define NEG_SLOPE 0.2f

typedef __attribute__((ext_vector_type(8))) short short8;
typedef __attribute__((ext_vector_type(4))) float f32x4;

static __device__ __forceinline__ unsigned short f2bf(float x) {
  uint32_t u = __float_as_uint(x);
  uint32_t r = (u + 0x7FFFu + ((u >> 16) & 1u)) >> 16;
  return (unsigned short)r;
}

// ---------------------------------------------------------------------------
// prep (grid 128 x 4):
//   z=0/1 -> W0/W1 transpose+cast to Wt[256][128] bf16
//   z=2, x=0 -> Q[h][k] = sum_d Wm[k][h*32+d]*attn_r[h][d]
//   z=2, x=1 -> zero the lookback-scan flag array (replay safety)
//   z=3 -> zero deg[Nm]
// ---------------------------------------------------------------------------
__global__ void prep_kernel(const float* __restrict__ W0, const float* __restrict__ W1,
                            const float* __restrict__ Wm, const float* __restrict__ ar,
                            unsigned short* __restrict__ T0, unsigned short* __restrict__ T1,
                            float* __restrict__ Q, int* __restrict__ deg, int Nm,
                            unsigned int* __restrict__ bstate) {
  const int z = blockIdx.y;
  const int t = threadIdx.x;
  if (z < 2) {
    const float* W = (z == 0) ? W0 : W1;
    unsigned short* T = (z == 0) ? T0 : T1;
    int c = blockIdx.x * 2 + (t >> 7);
    int k = t & 127;
    T[c * 128 + k] = f2bf(W[k * 256 + c]);
  } else if (z == 2) {
    if (blockIdx.x == 0) {
      #pragma unroll
      for (int q4 = 0; q4 < 4; ++q4) {
        int t2 = q4 * 256 + t;
        int k = t2 >> 3, h = t2 & 7;
        const float* wr = &Wm[k * 256 + h * 32];
        const float* av = &ar[h * 32];
        float s = 0.f;
        #pragma unroll
        for (int q = 0; q < 8; ++q) {
          float4 w4 = *(const float4*)(wr + q * 4);
          float4 a4 = *(const float4*)(av + q * 4);
          s += w4.x * a4.x + w4.y * a4.y + w4.z * a4.z + w4.w * a4.w;
        }
        Q[h * 128 + k] = s;
      }
    } else if (blockIdx.x == 1) {
      if (t < 64) bstate[t] = 0u;
    }
  } else {
    // z == 3: zero deg
    for (int i = blockIdx.x * 256 + t; i < Nm; i += 128 * 256)
      deg[i] = 0;
  }
}

// ---------------------------------------------------------------------------
// Fused: blocks [0, erb) -> er[n][h] = sum_k feats[n][k]*Q[h][k] (rank-8
// master projection, fp32); blocks [erb, erb+cb) -> degree count.
// ---------------------------------------------------------------------------
__global__ __launch_bounds__(256)
void er_count_kernel(const float* __restrict__ feats, const float* __restrict__ Q,
                     float* __restrict__ er, int N, int erb,
                     const int* __restrict__ dst0, int E0,
                     const int* __restrict__ dst1, int E1,
                     int* __restrict__ deg) {
  const int t = threadIdx.x;
  if (blockIdx.x >= erb) {
    int i = (blockIdx.x - erb) * 256 + t;
    int E = E0 + E1;
    if (i < E) {
      int d = (i < E0) ? dst0[i] : dst1[i - E0];
      atomicAdd(&deg[d], 1);
    }
    return;
  }

  __shared__ float Qs[8 * 128];
  ((float4*)Qs)[t] = ((const float4*)Q)[t];
  __syncthreads();

  const int lane = t & 63, wave = t >> 6;
  const int j = lane & 7;
  const int n = blockIdx.x * 32 + wave * 8 + (lane >> 3);
  const bool ok = n < N;

  float acc[8] = {};
  #pragma unroll
  for (int q = 0; q < 4; ++q) {
    float4 f = make_float4(0.f, 0.f, 0.f, 0.f);
    int kc = q * 32 + j * 4;
    if (ok) f = *(const float4*)(&feats[(size_t)n * 128 + kc]);
    #pragma unroll
    for (int h = 0; h < 8; ++h) {
      const float* qr = &Qs[h * 128 + kc];
      acc[h] = fmaf(f.x, qr[0], acc[h]);
      acc[h] = fmaf(f.y, qr[1], acc[h]);
      acc[h] = fmaf(f.z, qr[2], acc[h]);
      acc[h] = fmaf(f.w, qr[3], acc[h]);
    }
  }
  #pragma unroll
  for (int h = 0; h < 8; ++h) {
    acc[h] += __shfl_xor(acc[h], 1);
    acc[h] += __shfl_xor(acc[h], 2);
    acc[h] += __shfl_xor(acc[h], 4);
  }
  float out = acc[0];
  out = (j == 1) ? acc[1] : out;  out = (j == 2) ? acc[2] : out;
  out = (j == 3) ? acc[3] : out;  out = (j == 4) ? acc[4] : out;
  out = (j == 5) ? acc[5] : out;  out = (j == 6) ? acc[6] : out;
  out = (j == 7) ? acc[7] : out;
  if (ok) er[(size_t)n * 8 + j] = out;
}

// ---------------------------------------------------------------------------
// MFMA proj for the two attention-node types (z = 0 -> a0, z = 1 -> a1):
// ft = bf16(feats) @ bf16(W), el fused. Row tile 64 (LDS 16 KB), 4 waves
// each owning a different 64-col quarter. Wt fragments prefetched before
// staging; one barrier. Swapped-operand MFMA => D[ftcol][node]: lane l15 =
// node, regs = 4 consecutive ft cols -> direct ushort4 register stores.
// ---------------------------------------------------------------------------
__global__ __launch_bounds__(256)
void proj_mfma_kernel(const float* __restrict__ fa0, const float* __restrict__ fa1,
                      const unsigned short* __restrict__ Wt0,
                      const unsigned short* __restrict__ Wt1,
                      const float* __restrict__ attn_l,
                      int Na0, int Na1,
                      unsigned short* __restrict__ ft_all, float* __restrict__ el_all) {
  const int z = blockIdx.z;
  const float* feats = (z == 0) ? fa0 : fa1;
  const unsigned short* Wt = (z == 0) ? Wt0 : Wt1;
  const float* av = attn_l;
  const int N = (z == 0) ? Na0 : Na1;
  unsigned short* ft_out = (z == 0) ? ft_all : ft_all + (size_t)Na0 * 256;
  float* el_out = (z == 0) ? el_all : el_all + (size_t)Na0 * 8;

  const int rb = blockIdx.x * 64;
  if (rb >= N) return;

  __shared__ unsigned short As[64 * 128];   // 16 KB
  const int t = threadIdx.x;
  const int wid = t >> 6, lane = t & 63;
  const int l15 = lane & 15, l4 = lane >> 4;
  const int cbw = wid * 64;                 // this wave's col quarter
  const int head0 = cbw >> 5;               // 2 heads per wave

  // prefetch Wt fragments (L2-hot, no LDS dependency)
  short8 bf[4][4];                          // [kb][nf]
  #pragma unroll
  for (int nf = 0; nf < 4; ++nf) {
    const unsigned short* wp = &Wt[(size_t)(cbw + nf * 16 + l15) * 128];
    #pragma unroll
    for (int kb = 0; kb < 4; ++kb)
      bf[kb][nf] = *(const short8*)(wp + kb * 32 + l4 * 8);
  }

  // stage feats rows rb..rb+64: f32 -> bf16, swizzled, coalesced
  #pragma unroll
  for (int it = 0; it < 8; ++it) {
    int i = it * 256 + t;
    int r = i >> 5, kc = (i & 31) << 2;
    float4 f = make_float4(0.f, 0.f, 0.f, 0.f);
    if (rb + r < N) f = *(const float4*)(&feats[(size_t)(rb + r) * 128 + kc]);
    ushort4 u;
    u.x = f2bf(f.x); u.y = f2bf(f.y); u.z = f2bf(f.z); u.w = f2bf(f.w);
    uint32_t byte = ((uint32_t)(r * 256 + kc * 2)) ^ ((uint32_t)((r & 7) << 4));
    *(ushort4*)((char*)As + byte) = u;
  }
  __syncthreads();

  f32x4 acc[4][4];                          // [mf][nf]
  #pragma unroll
  for (int a = 0; a < 4; ++a)
    #pragma unroll
    for (int b = 0; b < 4; ++b)
      acc[a][b] = (f32x4){0.f, 0.f, 0.f, 0.f};

  #pragma unroll
  for (int kb = 0; kb < 4; ++kb) {
    short8 af[4];
    #pragma unroll
    for (int mf = 0; mf < 4; ++mf) {
      int row = mf * 16 + l15;
      uint32_t byte = ((uint32_t)(row * 256 + kb * 64 + l4 * 16)) ^ ((uint32_t)((row & 7) << 4));
      af[mf] = *(const short8*)((const char*)As + byte);
    }
    #pragma unroll
    for (int mf = 0; mf < 4; ++mf)
      #pragma unroll
      for (int nf = 0; nf < 4; ++nf)
        acc[mf][nf] = __builtin_amdgcn_mfma_f32_16x16x32_bf16(
            bf[kb][nf], af[mf], acc[mf][nf], 0, 0, 0);
  }

  float avf[4][4];
  #pragma unroll
  for (int nf = 0; nf < 4; ++nf)
    #pragma unroll
    for (int reg = 0; reg < 4; ++reg)
      avf[nf][reg] = av[(head0 + (nf >> 1)) * 32 + (nf & 1) * 16 + l4 * 4 + reg];

  #pragma unroll
  for (int mf = 0; mf < 4; ++mf) {
    int node = rb + mf * 16 + l15;
    bool ok = node < N;
    if (ok) {
      size_t base = (size_t)node * 256 + cbw + l4 * 4;
      #pragma unroll
      for (int nf = 0; nf < 4; ++nf) {
        ushort4 u;
        u.x = f2bf(acc[mf][nf][0]); u.y = f2bf(acc[mf][nf][1]);
        u.z = f2bf(acc[mf][nf][2]); u.w = f2bf(acc[mf][nf][3]);
        *(ushort4*)(&ft_out[base + nf * 16]) = u;
      }
    }
    #pragma unroll
    for (int hh = 0; hh < 2; ++hh) {
      float p = 0.f;
      #pragma unroll
      for (int reg = 0; reg < 4; ++reg) {
        p = fmaf(acc[mf][2 * hh][reg], avf[2 * hh][reg], p);
        p = fmaf(acc[mf][2 * hh + 1][reg], avf[2 * hh + 1][reg], p);
      }
      p += __shfl_xor(p, 16);
      p += __shfl_xor(p, 32);
      if (ok && l4 == 0)
        el_out[(size_t)node * 8 + head0 + hh] = p;
    }
  }
}

// ---------------------------------------------------------------------------
// Single-launch decoupled-lookback scan over deg[n] -> offs/cursor (+ total).
// 49 blocks x 1024 (all co-resident on 256 CUs -> lookback cannot deadlock).
// bstate[b] = (value << 2) | state; state 1 = aggregate ready, 2 = prefix
// ready. Zeroed each call by prep (replay-safe). Edge count < 2^20 << 2^30.
// ---------------------------------------------------------------------------
__global__ __launch_bounds__(1024)
void scan_kernel(const int* __restrict__ deg, int* __restrict__ offs,
                 int* __restrict__ cursor, int n, int nb,
                 unsigned int* __restrict__ bstate) {
  const int b = blockIdx.x, t = threadIdx.x;
  __shared__ int wsum[16];
  __shared__ int s_base;
  int idx = b * 1024 + t;
  int v = (idx < n) ? deg[idx] : 0;
  const int lane = t & 63, w = t >> 6;
  int incl = v;
  #pragma unroll
  for (int off = 1; off < 64; off <<= 1) {
    int x = __shfl_up(incl, off);
    if (lane >= off) incl += x;
  }
  if (lane == 63) wsum[w] = incl;
  __syncthreads();
  if (t < 16) {
    int x = wsum[t];
    #pragma unroll
    for (int off = 1; off < 16; off <<= 1) {
      int y = __shfl_up(x, off);
      if (t >= off) x += y;
    }
    wsum[t] = x;
  }
  __syncthreads();
  const int blockAgg = wsum[15];

  if (t == 0) {
    // publish: block 0's aggregate IS its prefix
    unsigned int pub = ((unsigned int)blockAgg << 2) | (b == 0 ? 2u : 1u);
    __hip_atomic_store(&bstate[b], pub, __ATOMIC_RELEASE, __HIP_MEMORY_SCOPE_AGENT);
    int exc = 0;
    if (b > 0) {
      int pb = b - 1;
      while (true) {
        unsigned int s = __hip_atomic_load(&bstate[pb], __ATOMIC_ACQUIRE,
                                           __HIP_MEMORY_SCOPE_AGENT);
        unsigned int st = s & 3u;
        if (st == 0u) continue;          // predecessor not ready yet
        exc += (int)(s >> 2);
        if (st == 2u) break;             // hit a full prefix: done
        --pb;                            // aggregate only: keep walking back
      }
      unsigned int pub2 = ((unsigned int)(exc + blockAgg) << 2) | 2u;
      __hip_atomic_store(&bstate[b], pub2, __ATOMIC_RELEASE, __HIP_MEMORY_SCOPE_AGENT);
    }
    s_base = exc;
    if (b == nb - 1) offs[n] = exc + blockAgg;   // grand total
  }
  __syncthreads();

  const int base = s_base;
  int excl = base + ((w > 0) ? wsum[w - 1] : 0) + incl - v;
  if (idx < n) {
    offs[idx] = excl;
    cursor[idx] = excl;
  }
}

// ---------------------------------------------------------------------------
// scatter: per edge, one 32-byte-aligned record {src, w[8] bf16} (20 B used)
// at the CSR slot, plain stores (records must stay L2-resident for
// aggregate's scalar reads -- nt here cost +12 us in R16).
// Weights are exp(lrelu(el[src]+er[dst])): single-pass softmax, O(1)-bounded.
// ---------------------------------------------------------------------------
__global__ void scatter_kernel(const int* __restrict__ src0, const int* __restrict__ dst0, int E0,
                               const int* __restrict__ src1, const int* __restrict__ dst1, int E1,
                               int* __restrict__ cursor, char* __restrict__ recs,
                               const float* __restrict__ el, const float* __restrict__ er,
                               int Na0) {
  int E = E0 + E1;
  int i = blockIdx.x * blockDim.x + threadIdx.x;
  if (i >= E) return;
  int s, d;
  if (i < E0) { s = src0[i]; d = dst0[i]; }
  else        { s = src1[i - E0] + Na0; d = dst1[i - E0]; }
  int pos = atomicAdd(&cursor[d], 1);

  const float* elp = &el[(size_t)s * 8];
  const float* erp = &er[(size_t)d * 8];
  float4 ea = *(const float4*)elp, eb = *(const float4*)(elp + 4);
  float4 ra = *(const float4*)erp, rb = *(const float4*)(erp + 4);
  float w[8];
  w[0] = ea.x + ra.x; w[1] = ea.y + ra.y; w[2] = ea.z + ra.z; w[3] = ea.w + ra.w;
  w[4] = eb.x + rb.x; w[5] = eb.y + rb.y; w[6] = eb.z + rb.z; w[7] = eb.w + rb.w;
  uint32_t pk[4];
  #pragma unroll
  for (int q = 0; q < 4; ++q) {
    float v0 = w[2 * q], v1 = w[2 * q + 1];
    v0 = fmaxf(v0, NEG_SLOPE * v0);
    v1 = fmaxf(v1, NEG_SLOPE * v1);
    uint32_t b0 = f2bf(__expf(v0)), b1 = f2bf(__expf(v1));
    pk[q] = b0 | (b1 << 16);
  }
  char* rp = recs + ((size_t)(uint32_t)pos << 5);
  *(uint4*)rp = make_uint4((uint32_t)s, pk[0], pk[1], pk[2]);
  *(uint32_t*)(rp + 16) = pk[3];
}

// ---------------------------------------------------------------------------
// one wave per dst node. Records are wave-uniform -> readfirstlane pins the
// record/offs loads to the SCALAR path; src lands in an SGPR so the ft gather
// is saddr + loop-invariant lane offset. Weight picked from 4 SGPRs by 3
// cndmask + shift.
// lane layout: h = lane>>3, d = (lane&7)*4 + j
// ---------------------------------------------------------------------------
__global__ __launch_bounds__(256)
void aggregate_kernel(const int* __restrict__ offs, const char* __restrict__ recs,
                      const unsigned short* __restrict__ ft,
                      float* __restrict__ rst, int Nm) {
  int gid = blockIdx.x * blockDim.x + threadIdx.x;
  int n = gid >> 6;
  int lane = threadIdx.x & 63;
  if (n >= Nm) return;
  const int nu = __builtin_amdgcn_readfirstlane(n);   // wave-uniform node id
  const int beg = offs[nu], end = offs[nu + 1];       // scalar loads
  const int h = lane >> 3;
  const char* ftl = (const char*)ft + lane * 8;
  float o0 = 0.f, o1 = 0.f, o2 = 0.f, o3 = 0.f;
  float sw = 0.f;

  #pragma unroll 8
  for (int i = beg; i < end; ++i) {
    const uint32_t* rp = (const uint32_t*)(recs + ((size_t)(uint32_t)i << 5));
    uint32_t sct = rp[0];                         // SGPR: src index
    uint32_t d0 = rp[1], d1 = rp[2], d2 = rp[3], d3 = rp[4];   // SGPR: weights
    uint2 g = *(const uint2*)(ftl + ((size_t)sct << 9));        // the only gather
    uint32_t wa = (h & 2) ? d1 : d0;
    uint32_t wb = (h & 2) ? d3 : d2;
    uint32_t wsl = (h & 4) ? wb : wa;
    float w = __uint_as_float((h & 1) ? (wsl & 0xffff0000u) : (wsl << 16));
    sw += w;
    o0 = fmaf(w, __uint_as_float(g.x << 16), o0);
    o1 = fmaf(w, __uint_as_float(g.x & 0xffff0000u), o1);
    o2 = fmaf(w, __uint_as_float(g.y << 16), o2);
    o3 = fmaf(w, __uint_as_float(g.y & 0xffff0000u), o3);
  }

  if (beg < end) {
    float inv = 1.0f / sw;
    o0 *= inv; o1 *= inv; o2 *= inv; o3 *= inv;
  }
  *(float4*)(&rst[(size_t)n * 256 + lane * 4]) = make_float4(o0, o1, o2, o3);
}

// ---------------------------------------------------------------------------
extern "C" void kernel_launch(void* const* d_in, const int* in_sizes, int n_in,
                              void* d_out, int out_size, void* d_ws, size_t ws_size,
                              hipStream_t stream) {
  const float* master = (const float*)d_in[0];
  const float* af0    = (const float*)d_in[1];
  const float* af1    = (const float*)d_in[2];
  const int*   src0   = (const int*)d_in[3];
  const int*   dst0   = (const int*)d_in[4];
  const int*   src1   = (const int*)d_in[5];
  const int*   dst1   = (const int*)d_in[6];
  const float* Wm     = (const float*)d_in[7];
  const float* W0     = (const float*)d_in[8];
  const float* W1     = (const float*)d_in[9];
  const float* attn_l = (const float*)d_in[10];
  const float* attn_r = (const float*)d_in[11];

  const int Nm  = in_sizes[0] / 128;
  const int Na0 = in_sizes[1] / 128;
  const int Na1 = in_sizes[2] / 128;
  const int E0  = in_sizes[3];
  const int E1  = in_sizes[5];
  float* rst = (float*)d_out;

  char* ws = (char*)d_ws;
  size_t off = 0;
  auto alloc = [&](size_t b) -> char* {
    char* p = ws + off;
    off += (b + 511) & ~(size_t)511;
    return p;
  };
  unsigned short* ft = (unsigned short*)alloc((size_t)(Na0 + Na1) * 256 * sizeof(unsigned short));
  float* el = (float*)alloc((size_t)(Na0 + Na1) * 8 * sizeof(float));
  float* er = (float*)alloc((size_t)Nm * 8 * sizeof(float));
  unsigned short* Wt0 = (unsigned short*)alloc(256 * 128 * sizeof(unsigned short));
  unsigned short* Wt1 = (unsigned short*)alloc(256 * 128 * sizeof(unsigned short));
  float* Q     = (float*)alloc(8 * 128 * sizeof(float));
  int* deg     = (int*)alloc((size_t)Nm * sizeof(int));
  int* offs    = (int*)alloc((size_t)(Nm + 1) * sizeof(int));
  int* cursor  = (int*)alloc((size_t)Nm * sizeof(int));
  unsigned int* bstate = (unsigned int*)alloc(64 * sizeof(unsigned int));
  char* recs   = alloc((size_t)(E0 + E1) * 32);

  const int E = E0 + E1;

  // 1) prep: Wt transpose+cast, Q collapse, zero deg + scan flags
  prep_kernel<<<dim3(128, 4), 256, 0, stream>>>(W0, W1, Wm, attn_r,
                                                Wt0, Wt1, Q, deg, Nm, bstate);

  // 2) er skinny GEMM + degree count, one launch
  const int erb = (Nm + 31) / 32;
  const int cb  = (E + 255) / 256;
  er_count_kernel<<<erb + cb, 256, 0, stream>>>(master, Q, er, Nm, erb,
                                                dst0, E0, dst1, E1, deg);

  // 3) attention-node projections (ft + el)
  int Nmax = Na0 > Na1 ? Na0 : Na1;
  const int mb = (Nmax + 63) / 64;
  proj_mfma_kernel<<<dim3(mb, 1, 2), 256, 0, stream>>>(
      af0, af1, Wt0, Wt1, attn_l, Na0, Na1, ft, el);

  // 4) single-launch decoupled-lookback scan
  const int nb = (Nm + 1023) / 1024;   // 49 <= 64
  scan_kernel<<<nb, 1024, 0, stream>>>(deg, offs, cursor, Nm, nb, bstate);

  // 5) scatter records
  scatter_kernel<<<cb, 256, 0, stream>>>(src0, dst0, E0, src1, dst1, E1,
                                         cursor, recs, el, er, Na0);

  // 6) aggregate
  aggregate_kernel<<<(Nm + 3) / 4, 256, 0, stream>>>(offs, recs, ft, rst, Nm);
}